// Round 4
// baseline (335.113 us; speedup 1.0000x reference)
//
#include <hip/hip_runtime.h>
#include <stdint.h>

#define N_NODES   50000
#define N_EDGES   800000
#define IN_DIM    128
#define OUT_DIM   128
#define NUM_RELS  8
#define THREADS   256

typedef _Float16 half_t;
typedef _Float16 half2v __attribute__((ext_vector_type(2)));
typedef _Float16 half4v __attribute__((ext_vector_type(4)));
typedef _Float16 half8 __attribute__((ext_vector_type(8)));
typedef float floatx4 __attribute__((ext_vector_type(4)));

// ============ plan ============
// 1. y2[n][r*128+c] = feat[n] @ W[r]  -- LDS-free MFMA GEMM, frags straight from global
// 2. counting-sort edges by dst; records (base = src*1024+rel*128, w f16)
// 3. block per dst: out[d] = sum_e w_e * y2[base_e : +128]  (4-wave split + LDS reduce)

#define NBINS3    N_NODES                         // 50000
#define NB3       ((NBINS3 + 1023) / 1024)        // 49

// ws layout (bytes) -- 107,662,208 total (same proven budget as round 3)
#define WS_Y2     0                               // y2   : 50000 x 1024 f16 (102,400,000)
#define WS_OFF    102400000                       // off  : 50001 i32 (200,004 -> pad 200,064)
#define WS_WT     102600064                       // WT   : 1024 x 128 f16 (262,144); hist/bsum alias after gemm
#define WS_HIST   WS_WT                           // hist/cursors : 50000 i32 (200,000)
#define WS_BSUM   (WS_WT + 200000)                // bsum : 49 i32
#define WS_BASE   102862208                       // base : N_EDGES i32 (3,200,000)
#define WS_WGT    106062208                       // wgt  : N_EDGES f16 (1,600,000)
#define WS_NEED   (size_t)107662208

// ---- sort: histogram over dst
__global__ void hist3_kernel(const int* __restrict__ dst, int* __restrict__ hist) {
    int i = blockIdx.x * blockDim.x + threadIdx.x;
    if (i < N_EDGES) atomicAdd(&hist[dst[i]], 1);
}

__global__ void scan1_kernel(const int* __restrict__ hist, int* __restrict__ bsum) {
    __shared__ int sh[256];
    int b = blockIdx.x, t = threadIdx.x;
    int i0 = b * 1024 + t * 4;
    int s = 0;
    #pragma unroll
    for (int j = 0; j < 4; j++) { int idx = i0 + j; if (idx < NBINS3) s += hist[idx]; }
    sh[t] = s; __syncthreads();
    for (int o = 128; o > 0; o >>= 1) { if (t < o) sh[t] += sh[t + o]; __syncthreads(); }
    if (t == 0) bsum[b] = sh[0];
}

// parallel exclusive scan over NB3 (<=64) block sums
__global__ void scan2_kernel(int* __restrict__ bsum, int* __restrict__ off) {
    __shared__ int sh[64];
    int t = threadIdx.x;
    int v = (t < NB3) ? bsum[t] : 0;
    sh[t] = v; __syncthreads();
    for (int o = 1; o < 64; o <<= 1) {
        int x = (t >= o) ? sh[t - o] : 0;
        __syncthreads();
        sh[t] += x;
        __syncthreads();
    }
    if (t < NB3) bsum[t] = sh[t] - v;
    if (t == 0) off[NBINS3] = N_EDGES;
}

__global__ void scan3_kernel(const int* __restrict__ hist, const int* __restrict__ boff,
                             int* __restrict__ off, int* __restrict__ cursors) {
    __shared__ int sh[256];
    int b = blockIdx.x, t = threadIdx.x;
    int i0 = b * 1024 + t * 4;
    int v[4]; int s = 0;
    #pragma unroll
    for (int j = 0; j < 4; j++) { int idx = i0 + j; v[j] = (idx < NBINS3) ? hist[idx] : 0; s += v[j]; }
    sh[t] = s; __syncthreads();
    for (int o = 1; o < 256; o <<= 1) {
        int x = (t >= o) ? sh[t - o] : 0;
        __syncthreads();
        sh[t] += x;
        __syncthreads();
    }
    int run = sh[t] - s + boff[b];
    #pragma unroll
    for (int j = 0; j < 4; j++) {
        int idx = i0 + j;
        if (idx < NBINS3) { off[idx] = run; cursors[idx] = run; }
        run += v[j];
    }
}

// scatter edge records: base = src*1024 + rel*128 (y2 row offset), w as f16
__global__ void scatter3_kernel(const int* __restrict__ dst, const int* __restrict__ src,
                                const int* __restrict__ rel, const float* __restrict__ ew,
                                int* __restrict__ cursors, int* __restrict__ base,
                                half_t* __restrict__ wgt) {
    int i = blockIdx.x * blockDim.x + threadIdx.x;
    if (i < N_EDGES) {
        int pos = atomicAdd(&cursors[dst[i]], 1);
        base[pos] = src[i] * 1024 + rel[i] * 128;
        wgt[pos] = (half_t)ew[i];
    }
}

// rel_emb [r][k][n] fp32  ->  WT [r*128+n][k] f16
__global__ void prep_wt_kernel(const float* __restrict__ rel_emb, half_t* __restrict__ WT) {
    int t = blockIdx.x * blockDim.x + threadIdx.x;
    if (t < NUM_RELS * 128 * 128) {
        int r = t >> 14, k = (t >> 7) & 127, n = t & 127;
        WT[(size_t)((r << 7) | n) * 128 + k] = (half_t)rel_emb[t];
    }
}

// ---- LDS-free GEMM: y2[50000 x 1024] = f16(feat) @ WT^T
// Operand swap: A = WT (M-dim = out-col n), B = feat (N-dim = node m).
// D: col(l16) = node, rows(q*4+reg) = 4 CONSECUTIVE n -> half4 packed stores.
template<bool GUARD>
__device__ __forceinline__ void gemm_body(const float* __restrict__ feat,
                                          const half_t* __restrict__ WT,
                                          half_t* __restrict__ y2,
                                          int m0, int n0, int wave, int lane) {
    const int q = lane >> 4, l16 = lane & 15;
    const int wm0 = m0 + wave * 32;               // this wave's 32 nodes

    floatx4 acc[8][2];
    #pragma unroll
    for (int nt = 0; nt < 8; nt++)
        #pragma unroll
        for (int ms = 0; ms < 2; ms++) acc[nt][ms] = (floatx4){0.f, 0.f, 0.f, 0.f};

    const half_t* Abase = WT + (size_t)(n0 + l16) * 128 + q * 8;
    const float*  Bbase = feat + (size_t)(wm0 + l16) * 128 + q * 8;

    #pragma unroll
    for (int ks = 0; ks < 128; ks += 32) {
        half8 b[2];
        #pragma unroll
        for (int ms = 0; ms < 2; ms++) {
            float4 f0 = {0.f, 0.f, 0.f, 0.f}, f1 = {0.f, 0.f, 0.f, 0.f};
            if (!GUARD || (wm0 + ms * 16 + l16) < N_NODES) {
                f0 = *(const float4*)(Bbase + ms * 16 * 128 + ks);
                f1 = *(const float4*)(Bbase + ms * 16 * 128 + ks + 4);
            }
            half8 hb;
            hb[0] = (half_t)f0.x; hb[1] = (half_t)f0.y; hb[2] = (half_t)f0.z; hb[3] = (half_t)f0.w;
            hb[4] = (half_t)f1.x; hb[5] = (half_t)f1.y; hb[6] = (half_t)f1.z; hb[7] = (half_t)f1.w;
            b[ms] = hb;
        }
        #pragma unroll
        for (int nt = 0; nt < 8; nt++) {
            half8 a = *(const half8*)(Abase + nt * 16 * 128 + ks);
            acc[nt][0] = __builtin_amdgcn_mfma_f32_16x16x32_f16(a, b[0], acc[nt][0], 0, 0, 0);
            acc[nt][1] = __builtin_amdgcn_mfma_f32_16x16x32_f16(a, b[1], acc[nt][1], 0, 0, 0);
        }
    }
    #pragma unroll
    for (int nt = 0; nt < 8; nt++)
        #pragma unroll
        for (int ms = 0; ms < 2; ms++) {
            int node = wm0 + ms * 16 + l16;
            int nn = n0 + nt * 16 + q * 4;
            if (!GUARD || node < N_NODES) {
                half4v hv;
                hv[0] = (half_t)acc[nt][ms][0]; hv[1] = (half_t)acc[nt][ms][1];
                hv[2] = (half_t)acc[nt][ms][2]; hv[3] = (half_t)acc[nt][ms][3];
                *(half4v*)(y2 + (size_t)node * 1024 + nn) = hv;
            }
        }
}

#define GY_GRID (391 * 8)
__global__ __launch_bounds__(THREADS) void gemm_y_kernel(
    const float* __restrict__ feat, const half_t* __restrict__ WT,
    half_t* __restrict__ y2) {
    int bid = blockIdx.x;
    int work = (bid & 7) * 391 + (bid >> 3);      // XCD gets contiguous m-chunk (~3.2 MB feat -> L2)
    int mt = work >> 3, nt8 = work & 7;
    const int m0 = mt * 128, n0 = nt8 * 128;
    const int wave = threadIdx.x >> 6, lane = threadIdx.x & 63;
    if (m0 + 128 <= N_NODES)
        gemm_body<false>(feat, WT, y2, m0, n0, wave, lane);
    else
        gemm_body<true>(feat, WT, y2, m0, n0, wave, lane);
}

// ---- block per dst: 4 waves stride the edge list, unroll-2, LDS reduce
__global__ __launch_bounds__(THREADS) void gather_kernel(
    const half_t* __restrict__ y2, const int* __restrict__ base,
    const half_t* __restrict__ wgt, const int* __restrict__ off,
    float* __restrict__ out) {
    __shared__ float red[4][128];
    const int d = blockIdx.x;
    const int t = threadIdx.x, w = t >> 6, lane = t & 63;
    const int beg = off[d], end = off[d + 1];
    const half_t* yb = y2 + lane * 2;
    float ax = 0.f, ay = 0.f;
    int e = beg + w;
    for (; e + 4 < end; e += 8) {
        int b0 = base[e], b1 = base[e + 4];
        float w0 = (float)wgt[e], w1 = (float)wgt[e + 4];
        half2v v0 = *(const half2v*)(yb + b0);
        half2v v1 = *(const half2v*)(yb + b1);
        ax += w0 * (float)v0[0] + w1 * (float)v1[0];
        ay += w0 * (float)v0[1] + w1 * (float)v1[1];
    }
    if (e < end) {
        int b0 = base[e];
        float w0 = (float)wgt[e];
        half2v v0 = *(const half2v*)(yb + b0);
        ax += w0 * (float)v0[0];
        ay += w0 * (float)v0[1];
    }
    *(float2*)&red[w][lane * 2] = make_float2(ax, ay);
    __syncthreads();
    if (t < 64) {
        int c = t * 2;
        float2 o;
        o.x = red[0][c] + red[1][c] + red[2][c] + red[3][c];
        o.y = red[0][c + 1] + red[1][c + 1] + red[2][c + 1] + red[3][c + 1];
        *(float2*)(out + (size_t)d * 128 + c) = o;
    }
}

// ---- fallback (tiny ws): wave-per-edge direct with atomics
__global__ void naive_kernel(const float* __restrict__ feat, const float* __restrict__ rel_emb,
                             const float* __restrict__ ew, const int* __restrict__ src,
                             const int* __restrict__ dst, const int* __restrict__ rel,
                             float* __restrict__ out) {
    int wave = (blockIdx.x * blockDim.x + threadIdx.x) >> 6;
    int lane = threadIdx.x & 63;
    if (wave >= N_EDGES) return;
    const float* f = feat + (size_t)src[wave] * IN_DIM;
    const float* W = rel_emb + (size_t)rel[wave] * IN_DIM * OUT_DIM;
    float w = ew[wave];
    float a0 = 0.f, a1 = 0.f;
    for (int k = 0; k < IN_DIM; k++) {
        float fv = f[k];
        a0 += fv * W[k * OUT_DIM + lane];
        a1 += fv * W[k * OUT_DIM + 64 + lane];
    }
    int d = dst[wave];
    atomicAdd(&out[(size_t)d * OUT_DIM + lane], a0 * w);
    atomicAdd(&out[(size_t)d * OUT_DIM + 64 + lane], a1 * w);
}

extern "C" void kernel_launch(void* const* d_in, const int* in_sizes, int n_in,
                              void* d_out, int out_size, void* d_ws, size_t ws_size,
                              hipStream_t stream) {
    const float* feat    = (const float*)d_in[0];
    const float* rel_emb = (const float*)d_in[1];
    const float* ew      = (const float*)d_in[2];
    const int*   src     = (const int*)d_in[3];
    const int*   dst     = (const int*)d_in[4];
    const int*   rel     = (const int*)d_in[5];
    float* out = (float*)d_out;

    const int eb = (N_EDGES + THREADS - 1) / THREADS;   // 3125

    if (ws_size >= WS_NEED) {
        char* ws = (char*)d_ws;
        half_t* y2    = (half_t*)(ws + WS_Y2);
        int*    off   = (int*)(ws + WS_OFF);
        half_t* WT    = (half_t*)(ws + WS_WT);
        int*    hist  = (int*)(ws + WS_HIST);   // aliases WT (dead after gemm)
        int*    bsum  = (int*)(ws + WS_BSUM);
        int*    basep = (int*)(ws + WS_BASE);
        half_t* wgt   = (half_t*)(ws + WS_WGT);

        // phase 1: transform (needs WT; runs before hist aliases it)
        prep_wt_kernel<<<(NUM_RELS * 128 * 128 + THREADS - 1) / THREADS, THREADS, 0, stream>>>(rel_emb, WT);
        gemm_y_kernel<<<GY_GRID, THREADS, 0, stream>>>(feat, WT, y2);
        // phase 2: counting sort by dst
        hipMemsetAsync(hist, 0, (size_t)NBINS3 * 4, stream);
        hist3_kernel<<<eb, THREADS, 0, stream>>>(dst, hist);
        scan1_kernel<<<NB3, 256, 0, stream>>>(hist, bsum);
        scan2_kernel<<<1, 64, 0, stream>>>(bsum, off);
        scan3_kernel<<<NB3, 256, 0, stream>>>(hist, bsum, off, hist);  // in-place -> cursors
        scatter3_kernel<<<eb, THREADS, 0, stream>>>(dst, src, rel, ew, hist, basep, wgt);
        // phase 3: aggregate
        gather_kernel<<<N_NODES, THREADS, 0, stream>>>(y2, basep, wgt, off, out);
    } else {
        hipMemsetAsync(d_out, 0, (size_t)out_size * sizeof(float), stream);
        const long long total = (long long)N_EDGES * 64;
        const int blocks = (int)((total + THREADS - 1) / THREADS);
        naive_kernel<<<blocks, THREADS, 0, stream>>>(feat, rel_emb, ew, src, dst, rel, out);
    }
}

// Round 5
// 269.311 us; speedup vs baseline: 1.2443x; 1.2443x over previous
//
#include <hip/hip_runtime.h>
#include <stdint.h>

#define N_NODES   50000
#define N_EDGES   800000
#define IN_DIM    128
#define OUT_DIM   128
#define NUM_RELS  8
#define THREADS   256

typedef _Float16 half_t;
typedef _Float16 half2v __attribute__((ext_vector_type(2)));
typedef _Float16 half4v __attribute__((ext_vector_type(4)));
typedef _Float16 half8 __attribute__((ext_vector_type(8)));
typedef float floatx4 __attribute__((ext_vector_type(4)));

// ============ plan ============
// 1. y2[n][r*128+c] = feat[n] @ W[r]  -- MFMA GEMM: WT tile in swizzled LDS, feat hoisted to regs
// 2. counting-sort edges by dst; records (base = src*1024+rel*128, w f16)
// 3. wave per dst, unroll-8: out[d] = sum_e w_e * y2[base_e : +128]  (no atomics)

#define NBINS3    N_NODES                         // 50000
#define NB3       ((NBINS3 + 1023) / 1024)        // 49

// ws layout (bytes)
#define WS_Y2     0                               // y2   : 50000 x 1024 f16 (102,400,000)
#define WS_OFF    102400000                       // off  : 50001 i32 (pad to 200,064)
#define WS_WT     102600064                       // WT   : 1024 x 128 f16 (262,144)
#define WS_BASE   102862208                       // base : N_EDGES i32 (3,200,000)
#define WS_WGT    106062208                       // wgt  : N_EDGES f16 (1,600,000)
#define WS_HIST   107662208                       // hist/cursors : 50000 i32 (200,000)
#define WS_BSUM   107862208                       // bsum : 49 i32
#define WS_NEED   (size_t)107862464               // <= 109,063,728 proven available

// ---- fused: WT transpose-convert + dst histogram (independent ranges)
__global__ void prep_hist_kernel(const float* __restrict__ rel_emb, half_t* __restrict__ WT,
                                 const int* __restrict__ dst, int* __restrict__ hist) {
    int b = blockIdx.x;
    if (b < 512) {                                 // 512*256 = 131072 = 8*128*128 exactly
        int t = b * 256 + threadIdx.x;
        int r = t >> 14, k = (t >> 7) & 127, n = t & 127;
        WT[(size_t)((r << 7) | n) * 128 + k] = (half_t)rel_emb[t];
    } else {
        int i = (b - 512) * 256 + threadIdx.x;
        if (i < N_EDGES) atomicAdd(&hist[dst[i]], 1);
    }
}

__global__ void scan1_kernel(const int* __restrict__ hist, int* __restrict__ bsum) {
    __shared__ int sh[256];
    int b = blockIdx.x, t = threadIdx.x;
    int i0 = b * 1024 + t * 4;
    int s = 0;
    #pragma unroll
    for (int j = 0; j < 4; j++) { int idx = i0 + j; if (idx < NBINS3) s += hist[idx]; }
    sh[t] = s; __syncthreads();
    for (int o = 128; o > 0; o >>= 1) { if (t < o) sh[t] += sh[t + o]; __syncthreads(); }
    if (t == 0) bsum[b] = sh[0];
}

__global__ void scan2_kernel(int* __restrict__ bsum, int* __restrict__ off) {
    __shared__ int sh[64];
    int t = threadIdx.x;
    int v = (t < NB3) ? bsum[t] : 0;
    sh[t] = v; __syncthreads();
    for (int o = 1; o < 64; o <<= 1) {
        int x = (t >= o) ? sh[t - o] : 0;
        __syncthreads();
        sh[t] += x;
        __syncthreads();
    }
    if (t < NB3) bsum[t] = sh[t] - v;
    if (t == 0) off[NBINS3] = N_EDGES;
}

__global__ void scan3_kernel(const int* __restrict__ hist, const int* __restrict__ boff,
                             int* __restrict__ off, int* __restrict__ cursors) {
    __shared__ int sh[256];
    int b = blockIdx.x, t = threadIdx.x;
    int i0 = b * 1024 + t * 4;
    int v[4]; int s = 0;
    #pragma unroll
    for (int j = 0; j < 4; j++) { int idx = i0 + j; v[j] = (idx < NBINS3) ? hist[idx] : 0; s += v[j]; }
    sh[t] = s; __syncthreads();
    for (int o = 1; o < 256; o <<= 1) {
        int x = (t >= o) ? sh[t - o] : 0;
        __syncthreads();
        sh[t] += x;
        __syncthreads();
    }
    int run = sh[t] - s + boff[b];
    #pragma unroll
    for (int j = 0; j < 4; j++) {
        int idx = i0 + j;
        if (idx < NBINS3) { off[idx] = run; cursors[idx] = run; }
        run += v[j];
    }
}

__global__ void scatter3_kernel(const int* __restrict__ dst, const int* __restrict__ src,
                                const int* __restrict__ rel, const float* __restrict__ ew,
                                int* __restrict__ cursors, int* __restrict__ base,
                                half_t* __restrict__ wgt) {
    int i = blockIdx.x * blockDim.x + threadIdx.x;
    if (i < N_EDGES) {
        int pos = atomicAdd(&cursors[dst[i]], 1);
        base[pos] = src[i] * 1024 + rel[i] * 128;
        wgt[pos] = (half_t)ew[i];
    }
}

// ---- GEMM: y2[50000 x 1024] = f16(feat) @ WT^T
// A = WT (M = out-col), B = feat (N = node).  WT tile in LDS, chunk-XOR swizzled:
// element (row,k) lives at half-offset row*128 + ((k>>3 ^ (row&7))<<3) + (k&7).
// Reads and b128 writes both sweep all 32 banks -> conflict-free, no padding.
template<bool GUARD>
__device__ __forceinline__ void gemm_body(const float* __restrict__ feat,
                                          const half_t* __restrict__ Ws,   // LDS
                                          half_t* __restrict__ y2,
                                          int m0, int n0, int wave, int lane) {
    const int q = lane >> 4, l16 = lane & 15;
    const int wm0 = m0 + wave * 32;

    // hoist all feat loads (16 x float4 = 64 VGPR), independent of the barrier
    float4 fr[2][4][2];
    #pragma unroll
    for (int ms = 0; ms < 2; ms++) {
        int node = wm0 + ms * 16 + l16;
        const float* fb = feat + (size_t)node * 128 + q * 8;
        bool ok = !GUARD || node < N_NODES;
        #pragma unroll
        for (int kk = 0; kk < 4; kk++)
            #pragma unroll
            for (int h = 0; h < 2; h++) {
                float4 v = {0.f, 0.f, 0.f, 0.f};
                if (ok) v = *(const float4*)(fb + kk * 32 + h * 4);
                fr[ms][kk][h] = v;
            }
    }
    __syncthreads();   // Ws staged

    // convert to B-fragments
    half8 bf[2][4];
    #pragma unroll
    for (int ms = 0; ms < 2; ms++)
        #pragma unroll
        for (int kk = 0; kk < 4; kk++) {
            half8 hb;
            hb[0] = (half_t)fr[ms][kk][0].x; hb[1] = (half_t)fr[ms][kk][0].y;
            hb[2] = (half_t)fr[ms][kk][0].z; hb[3] = (half_t)fr[ms][kk][0].w;
            hb[4] = (half_t)fr[ms][kk][1].x; hb[5] = (half_t)fr[ms][kk][1].y;
            hb[6] = (half_t)fr[ms][kk][1].z; hb[7] = (half_t)fr[ms][kk][1].w;
            bf[ms][kk] = hb;
        }

    floatx4 acc[8][2];
    #pragma unroll
    for (int nt = 0; nt < 8; nt++)
        #pragma unroll
        for (int ms = 0; ms < 2; ms++) acc[nt][ms] = (floatx4){0.f, 0.f, 0.f, 0.f};

    #pragma unroll
    for (int kk = 0; kk < 4; kk++) {
        #pragma unroll
        for (int nt = 0; nt < 8; nt++) {
            int row = nt * 16 + l16;
            int phys = (kk * 4 + q) ^ (l16 & 7);
            half8 a = *(const half8*)(Ws + row * 128 + phys * 8);
            acc[nt][0] = __builtin_amdgcn_mfma_f32_16x16x32_f16(a, bf[0][kk], acc[nt][0], 0, 0, 0);
            acc[nt][1] = __builtin_amdgcn_mfma_f32_16x16x32_f16(a, bf[1][kk], acc[nt][1], 0, 0, 0);
        }
    }

    // D: col(l16)=node, rows(q*4+reg)=4 consecutive out-cols -> packed half4 stores
    #pragma unroll
    for (int nt = 0; nt < 8; nt++)
        #pragma unroll
        for (int ms = 0; ms < 2; ms++) {
            int node = wm0 + ms * 16 + l16;
            int nn = n0 + nt * 16 + q * 4;
            if (!GUARD || node < N_NODES) {
                half4v hv;
                hv[0] = (half_t)acc[nt][ms][0]; hv[1] = (half_t)acc[nt][ms][1];
                hv[2] = (half_t)acc[nt][ms][2]; hv[3] = (half_t)acc[nt][ms][3];
                *(half4v*)(y2 + (size_t)node * 1024 + nn) = hv;
            }
        }
}

#define GY_GRID (391 * 8)
__global__ __launch_bounds__(THREADS) void gemm_y_kernel(
    const float* __restrict__ feat, const half_t* __restrict__ WT,
    half_t* __restrict__ y2) {
    __shared__ half_t Ws[128 * 128];               // 32 KB, swizzled
    int bid = blockIdx.x;
    int work = (bid & 7) * 391 + (bid >> 3);       // XCD-contiguous m-chunks
    int mt = work >> 3, nt8 = work & 7;
    const int m0 = mt * 128, n0 = nt8 * 128;
    const int t = threadIdx.x;
    const int wave = t >> 6, lane = t & 63;

    // stage WT tile: 128 rows x 16 chunks of 8 halfs
    for (int i = t; i < 2048; i += THREADS) {
        int row = i >> 4, lc = i & 15;
        int phys = lc ^ (row & 7);
        *(uint4*)&Ws[row * 128 + phys * 8] =
            *(const uint4*)(WT + (size_t)(n0 + row) * 128 + lc * 8);
    }
    if (m0 + 128 <= N_NODES)
        gemm_body<false>(feat, Ws, y2, m0, n0, wave, lane);
    else
        gemm_body<true>(feat, Ws, y2, m0, n0, wave, lane);
}

// ---- wave per dst, unroll-8, dual accumulators
__global__ __launch_bounds__(THREADS) void gather_kernel(
    const half_t* __restrict__ y2, const int* __restrict__ base,
    const half_t* __restrict__ wgt, const int* __restrict__ off,
    float* __restrict__ out) {
    int g = blockIdx.x * 4 + (threadIdx.x >> 6);
    int lane = threadIdx.x & 63;
    int beg = off[g], end = off[g + 1];
    const half_t* yb = y2 + lane * 2;
    float ax = 0.f, ay = 0.f, cx = 0.f, cy = 0.f;
    int e = beg;
    for (; e + 8 <= end; e += 8) {
        int b0 = base[e], b1 = base[e + 1], b2 = base[e + 2], b3 = base[e + 3];
        int b4 = base[e + 4], b5 = base[e + 5], b6 = base[e + 6], b7 = base[e + 7];
        half2v v0 = *(const half2v*)(yb + b0);
        half2v v1 = *(const half2v*)(yb + b1);
        half2v v2 = *(const half2v*)(yb + b2);
        half2v v3 = *(const half2v*)(yb + b3);
        half2v v4 = *(const half2v*)(yb + b4);
        half2v v5 = *(const half2v*)(yb + b5);
        half2v v6 = *(const half2v*)(yb + b6);
        half2v v7 = *(const half2v*)(yb + b7);
        float w0 = (float)wgt[e],     w1 = (float)wgt[e + 1];
        float w2 = (float)wgt[e + 2], w3 = (float)wgt[e + 3];
        float w4 = (float)wgt[e + 4], w5 = (float)wgt[e + 5];
        float w6 = (float)wgt[e + 6], w7 = (float)wgt[e + 7];
        ax += w0 * (float)v0[0] + w1 * (float)v1[0];
        ay += w0 * (float)v0[1] + w1 * (float)v1[1];
        cx += w2 * (float)v2[0] + w3 * (float)v3[0];
        cy += w2 * (float)v2[1] + w3 * (float)v3[1];
        ax += w4 * (float)v4[0] + w5 * (float)v5[0];
        ay += w4 * (float)v4[1] + w5 * (float)v5[1];
        cx += w6 * (float)v6[0] + w7 * (float)v7[0];
        cy += w6 * (float)v6[1] + w7 * (float)v7[1];
    }
    for (; e + 2 <= end; e += 2) {
        int b0 = base[e], b1 = base[e + 1];
        float w0 = (float)wgt[e], w1 = (float)wgt[e + 1];
        half2v v0 = *(const half2v*)(yb + b0);
        half2v v1 = *(const half2v*)(yb + b1);
        ax += w0 * (float)v0[0] + w1 * (float)v1[0];
        ay += w0 * (float)v0[1] + w1 * (float)v1[1];
    }
    if (e < end) {
        int b0 = base[e];
        float w0 = (float)wgt[e];
        half2v v0 = *(const half2v*)(yb + b0);
        cx += w0 * (float)v0[0];
        cy += w0 * (float)v0[1];
    }
    float2 o; o.x = ax + cx; o.y = ay + cy;
    *(float2*)(out + (size_t)g * 128 + lane * 2) = o;
}

// ---- fallback (tiny ws): wave-per-edge direct with atomics
__global__ void naive_kernel(const float* __restrict__ feat, const float* __restrict__ rel_emb,
                             const float* __restrict__ ew, const int* __restrict__ src,
                             const int* __restrict__ dst, const int* __restrict__ rel,
                             float* __restrict__ out) {
    int wave = (blockIdx.x * blockDim.x + threadIdx.x) >> 6;
    int lane = threadIdx.x & 63;
    if (wave >= N_EDGES) return;
    const float* f = feat + (size_t)src[wave] * IN_DIM;
    const float* W = rel_emb + (size_t)rel[wave] * IN_DIM * OUT_DIM;
    float w = ew[wave];
    float a0 = 0.f, a1 = 0.f;
    for (int k = 0; k < IN_DIM; k++) {
        float fv = f[k];
        a0 += fv * W[k * OUT_DIM + lane];
        a1 += fv * W[k * OUT_DIM + 64 + lane];
    }
    int d = dst[wave];
    atomicAdd(&out[(size_t)d * OUT_DIM + lane], a0 * w);
    atomicAdd(&out[(size_t)d * OUT_DIM + 64 + lane], a1 * w);
}

extern "C" void kernel_launch(void* const* d_in, const int* in_sizes, int n_in,
                              void* d_out, int out_size, void* d_ws, size_t ws_size,
                              hipStream_t stream) {
    const float* feat    = (const float*)d_in[0];
    const float* rel_emb = (const float*)d_in[1];
    const float* ew      = (const float*)d_in[2];
    const int*   src     = (const int*)d_in[3];
    const int*   dst     = (const int*)d_in[4];
    const int*   rel     = (const int*)d_in[5];
    float* out = (float*)d_out;

    const int eb = (N_EDGES + THREADS - 1) / THREADS;   // 3125

    if (ws_size >= WS_NEED) {
        char* ws = (char*)d_ws;
        half_t* y2    = (half_t*)(ws + WS_Y2);
        int*    off   = (int*)(ws + WS_OFF);
        half_t* WT    = (half_t*)(ws + WS_WT);
        int*    basep = (int*)(ws + WS_BASE);
        half_t* wgt   = (half_t*)(ws + WS_WGT);
        int*    hist  = (int*)(ws + WS_HIST);
        int*    bsum  = (int*)(ws + WS_BSUM);

        hipMemsetAsync(hist, 0, (size_t)NBINS3 * 4, stream);
        prep_hist_kernel<<<512 + eb, THREADS, 0, stream>>>(rel_emb, WT, dst, hist);
        gemm_y_kernel<<<GY_GRID, THREADS, 0, stream>>>(feat, WT, y2);
        scan1_kernel<<<NB3, 256, 0, stream>>>(hist, bsum);
        scan2_kernel<<<1, 64, 0, stream>>>(bsum, off);
        scan3_kernel<<<NB3, 256, 0, stream>>>(hist, bsum, off, hist);  // in-place -> cursors
        scatter3_kernel<<<eb, THREADS, 0, stream>>>(dst, src, rel, ew, hist, basep, wgt);
        gather_kernel<<<N_NODES / 4, THREADS, 0, stream>>>(y2, basep, wgt, off, out);
    } else {
        hipMemsetAsync(d_out, 0, (size_t)out_size * sizeof(float), stream);
        const long long total = (long long)N_EDGES * 64;
        const int blocks = (int)((total + THREADS - 1) / THREADS);
        naive_kernel<<<blocks, THREADS, 0, stream>>>(feat, rel_emb, ew, src, dst, rel, out);
    }
}